// Round 14
// baseline (768.523 us; speedup 1.0000x reference)
//
#include <hip/hip_runtime.h>
#include <math.h>

#define N_NODES 50000
#define N_EDGES 600000
#define FATOM   78
#define DIM     128
#define HEADS   8
#define EDIM    12
#define LAYERS  4
#define NBATCH  512
#define NDFF    512
#define ASCALE  0.25f   // 1/sqrt(16)

typedef __attribute__((ext_vector_type(8))) short bf16x8;
typedef __attribute__((ext_vector_type(4))) float f32x4;

__device__ __forceinline__ float sum16(float v){
  #pragma unroll
  for (int m=1;m<16;m<<=1) v += __shfl_xor(v, m);
  return v;
}
__device__ __forceinline__ short f2b(float f){
  unsigned int u = __builtin_bit_cast(unsigned int, f);
  u += 0x7fffu + ((u>>16)&1u);
  return (short)(u>>16);
}
__device__ __forceinline__ float b2f_lo(unsigned int u){ return __builtin_bit_cast(float, u<<16); }
__device__ __forceinline__ float b2f_hi(unsigned int u){ return __builtin_bit_cast(float, u & 0xffff0000u); }
__device__ __forceinline__ float b2f_s(short s){
  return __builtin_bit_cast(float, ((unsigned int)(unsigned short)s)<<16);
}
__device__ __forceinline__ void unp8(uint4 u, float* o){
  o[0]=b2f_lo(u.x); o[1]=b2f_hi(u.x); o[2]=b2f_lo(u.y); o[3]=b2f_hi(u.y);
  o[4]=b2f_lo(u.z); o[5]=b2f_hi(u.z); o[6]=b2f_lo(u.w); o[7]=b2f_hi(u.w);
}

__device__ __forceinline__ void gload16(const short* g, short* l){
  __builtin_amdgcn_global_load_lds(
      (const __attribute__((address_space(1))) void*)g,
      (__attribute__((address_space(3))) void*)l, 16, 0, 0);
}

// ---------------- CSR build ----------------
__global__ void count_kernel(const int* __restrict__ ei, int* __restrict__ cnt){
  int e = blockIdx.x*256 + threadIdx.x;
  if (e < N_EDGES) atomicAdd(&cnt[ei[N_EDGES + e]], 1);
}

__global__ __launch_bounds__(1024) void scan1(const int* __restrict__ cnt,
                                              int* __restrict__ row_start, int* __restrict__ bsum){
  __shared__ int lds[1024];
  int gid = blockIdx.x*1024 + threadIdx.x;
  int v = (gid < N_NODES) ? cnt[gid] : 0;
  lds[threadIdx.x] = v; __syncthreads();
  for (int off=1; off<1024; off<<=1){
    int add = (threadIdx.x>=off)?lds[threadIdx.x-off]:0;
    __syncthreads();
    lds[threadIdx.x]+=add;
    __syncthreads();
  }
  if (gid < N_NODES) row_start[gid+1] = lds[threadIdx.x];
  if (threadIdx.x==1023) bsum[blockIdx.x] = lds[1023];
}
__global__ void scan2(int* __restrict__ bsum, int nb){
  int tid = threadIdx.x;
  int v = (tid < nb) ? bsum[tid] : 0;
  #pragma unroll
  for (int off=1; off<64; off<<=1){
    int u = __shfl_up(v, off);
    if (tid >= off) v += u;
  }
  if (tid < nb) bsum[tid] = v;   // inclusive
}
__global__ void scan3(int* __restrict__ row_start, const int* __restrict__ bsum){
  int gid = blockIdx.x*256 + threadIdx.x;
  if (gid == 0) row_start[0] = 0;
  if (gid < N_NODES){
    int blk = gid >> 10;
    if (blk > 0) row_start[gid+1] += bsum[blk-1];
  }
}

// edges into dst-CSR order; src id + bf16 edge_attr gathered into sorted order
__global__ void scatter_kernel(const int* __restrict__ ei, const float* __restrict__ ea,
                               int* __restrict__ cnt2, const int* __restrict__ row_start,
                               int* __restrict__ src_s, short* __restrict__ ea_s){
  int e = blockIdx.x*256 + threadIdx.x;
  if (e < N_EDGES){
    int d = ei[N_EDGES + e];
    int pos = atomicAdd(&cnt2[d], 1);
    int p = row_start[d] + pos;
    src_s[p] = ei[e];
    const float* src = ea + (size_t)e*EDIM;
    unsigned int* dst = (unsigned int*)(ea_s + (size_t)p*EDIM);
    #pragma unroll
    for (int j=0;j<6;j++){
      unsigned int lo = (unsigned int)(unsigned short)f2b(src[2*j]);
      unsigned int hi = (unsigned int)(unsigned short)f2b(src[2*j+1]);
      dst[j] = lo | (hi<<16);
    }
  }
}

// ---------------- degree sort (block-aggregated counting sort) ----------------
__global__ __launch_bounds__(256) void deg_hist(const int* __restrict__ cnt, int* __restrict__ dhist){
  __shared__ int lh[256];
  lh[threadIdx.x] = 0; __syncthreads();
  int n = blockIdx.x*256 + threadIdx.x;
  if (n < N_NODES){
    int d = cnt[n]; if (d > 255) d = 255;
    atomicAdd(&lh[d], 1);
  }
  __syncthreads();
  int c = lh[threadIdx.x];
  if (c) atomicAdd(&dhist[threadIdx.x], c);
}
__global__ __launch_bounds__(256) void deg_scan(const int* __restrict__ dhist, int* __restrict__ dstart){
  __shared__ int l[256];
  int t = threadIdx.x;
  int v = dhist[t];
  l[t] = v; __syncthreads();
  for (int off=1; off<256; off<<=1){
    int add = (t>=off)? l[t-off]:0;
    __syncthreads();
    l[t]+=add;
    __syncthreads();
  }
  dstart[t] = l[t]-v;   // exclusive
}
__global__ __launch_bounds__(256) void deg_place(const int* __restrict__ cnt, int* __restrict__ dcnt,
                                                 const int* __restrict__ dstart, int* __restrict__ perm){
  __shared__ int lh[256];
  __shared__ int lbase[256];
  __shared__ int lrank[256];
  int t = threadIdx.x;
  lh[t] = 0; lrank[t] = 0; __syncthreads();
  int n = blockIdx.x*256 + t;
  int d = -1;
  if (n < N_NODES){
    d = cnt[n]; if (d > 255) d = 255;
    atomicAdd(&lh[d], 1);
  }
  __syncthreads();
  int c = lh[t];
  lbase[t] = c ? atomicAdd(&dcnt[t], c) : 0;
  __syncthreads();
  if (n < N_NODES){
    int r = atomicAdd(&lrank[d], 1);
    perm[dstart[d] + lbase[d] + r] = n;
  }
}

// ---------------- weight packing: transpose to [M][K] bf16 ----------------
__global__ __launch_bounds__(256) void pack_weights(
  const float* __restrict__ Wq, const float* __restrict__ Wk,
  const float* __restrict__ Wv, const float* __restrict__ Ws,
  const float* __restrict__ bq, const float* __restrict__ bk,
  const float* __restrict__ bv, const float* __restrict__ bs,
  const float* __restrict__ Wf1, const float* __restrict__ Wf2,
  short* __restrict__ wq_t, short* __restrict__ wf1_t, short* __restrict__ wf2_t,
  float* __restrict__ bqkvs)
{
  int l = blockIdx.y;
  int idx = blockIdx.x*256 + threadIdx.x;   // 0 .. 3*65536-1
  int sec = idx >> 16, r = idx & 65535;
  if (sec == 0){
    int n = r >> 7, k = r & 127;
    const float* W = (n<128)?Wq:(n<256)?Wk:(n<384)?Wv:Ws;
    float v = W[(size_t)l*16384 + k*128 + (n&127)];
    wq_t[(size_t)l*65536 + n*128 + k] = f2b(v);
    if (k == 0){
      const float* bb = (n<128)?bq:(n<256)?bk:(n<384)?bv:bs;
      bqkvs[l*512 + n] = bb[l*128 + (n&127)];
    }
  } else if (sec == 1){
    int n = r >> 7, k = r & 127;
    wf1_t[(size_t)l*65536 + n*128 + k] = f2b(Wf1[(size_t)l*65536 + k*512 + n]);
  } else {
    int n = r >> 9, k = r & 511;
    wf2_t[(size_t)l*65536 + n*512 + k] = f2b(Wf2[(size_t)l*65536 + k*128 + n]);
  }
}

__global__ void pack_emb(const float* __restrict__ Wemb, short* __restrict__ wemb_t){
  int idx = blockIdx.x*256 + threadIdx.x;     // 128*128
  int nn = idx >> 7, k = idx & 127;
  wemb_t[nn*128 + k] = (k < FATOM) ? f2b(Wemb[(size_t)k*DIM + nn]) : (short)0;
}

__global__ void cast_pad_x(const float* __restrict__ x, short* __restrict__ xb){
  int idx = blockIdx.x*256 + threadIdx.x;     // N*64 u32-pairs
  int n = idx >> 6, kp = (idx & 63)*2;
  if (n >= N_NODES) return;
  float v0 = (kp   < FATOM) ? x[(size_t)n*FATOM + kp]   : 0.f;
  float v1 = (kp+1 < FATOM) ? x[(size_t)n*FATOM + kp+1] : 0.f;
  unsigned int lo = (unsigned int)(unsigned short)f2b(v0);
  unsigned int hi = (unsigned int)(unsigned short)f2b(v1);
  *(unsigned int*)(xb + (size_t)n*128 + kp) = lo | (hi<<16);
}

// ---------------- single-stage K=128 MFMA GEMM (generic, bf16 out; embed only) ----------------
__global__ __launch_bounds__(256) void gemm_k128(
    const short* __restrict__ A,   // bf16 [N][128]
    const short* __restrict__ Bt,  // bf16 [M][128]
    const float* __restrict__ bias,
    short* __restrict__ Cb,        // bf16 out
    int Nrows, int M, int relu, int nbn)
{
  __shared__ short As[128*128];
  __shared__ short Bs[128*128];
  int tid  = threadIdx.x;
  int lane = tid & 63;
  int wave = tid >> 6;
  int wr = wave >> 1, wc = wave & 1;
  int bm = blockIdx.x * 128;
  int d  = lane & 15;
  int lr = lane >> 4;

  #pragma unroll
  for (int it=0; it<8; ++it){
    int r = wave*32 + it*4 + lr;
    int oct = (d & 8) | ((d & 7) ^ (r & 7));
    int gr = bm + r; if (gr >= Nrows) gr = Nrows-1;
    gload16(A + (size_t)gr*128 + oct*8, As + (wave*32 + it*4)*128);
  }

  for (int t=0; t<nbn; ++t){
    int bn = (blockIdx.y*nbn + t)*128;
    if (t) __syncthreads();
    #pragma unroll
    for (int it=0; it<8; ++it){
      int r = wave*32 + it*4 + lr;
      int oct = (d & 8) | ((d & 7) ^ (r & 7));
      gload16(Bt + (size_t)(bn + r)*128 + oct*8, Bs + (wave*32 + it*4)*128);
    }
    f32x4 zero = {0.f,0.f,0.f,0.f};
    f32x4 acc[4][4];
    #pragma unroll
    for (int m=0;m<4;m++)
      #pragma unroll
      for (int n=0;n<4;n++) acc[m][n] = zero;

    __syncthreads();

    #pragma unroll
    for (int ks=0; ks<4; ++ks){
      int oi = ks*4 + lr;
      bf16x8 af[4], bfv[4];
      #pragma unroll
      for (int m=0;m<4;m++){
        int row = wr*64 + m*16 + d;
        int slot = (oi&8) | ((oi&7) ^ (row&7));
        af[m] = *(const bf16x8*)(As + row*128 + slot*8);
      }
      #pragma unroll
      for (int n=0;n<4;n++){
        int col = wc*64 + n*16 + d;
        int slot = (oi&8) | ((oi&7) ^ (col&7));
        bfv[n] = *(const bf16x8*)(Bs + col*128 + slot*8);
      }
      #pragma unroll
      for (int m=0;m<4;m++)
        #pragma unroll
        for (int n=0;n<4;n++)
          acc[m][n] = __builtin_amdgcn_mfma_f32_16x16x32_bf16(af[m], bfv[n], acc[m][n], 0, 0, 0);
    }

    #pragma unroll
    for (int m=0;m<4;m++){
      #pragma unroll
      for (int n=0;n<4;n++){
        int col = bn + wc*64 + n*16 + d;
        float bval = bias[col];
        #pragma unroll
        for (int j=0;j<4;j++){
          int row = bm + wr*64 + m*16 + lr*4 + j;
          if (row < Nrows){
            float v = acc[m][n][j] + bval;
            if (relu) v = fmaxf(v, 0.f);
            Cb[(size_t)row*M + col] = f2b(v);
          }
        }
      }
    }
  }
}

// ---------------- QKVS GEMM: 64-row strips (48KB LDS -> 3 blocks/CU) ----------------
// writes kv[N][256]=k|v and qx[N][256]=q|xr
__global__ __launch_bounds__(256) void gemm_qkvs(
    const short* __restrict__ A,   // bf16 [N][128]
    const short* __restrict__ Bt,  // bf16 [512][128]
    const float* __restrict__ bias,
    short* __restrict__ kv, short* __restrict__ qx,
    int Nrows)
{
  __shared__ short As[64*128];    // 16KB
  __shared__ short Bs[128*128];   // 32KB
  int tid  = threadIdx.x;
  int lane = tid & 63;
  int wave = tid >> 6;
  int wr = wave >> 1, wc = wave & 1;
  int bm = blockIdx.x * 64;
  int d  = lane & 15;
  int lr = lane >> 4;

  // stage A strip 64x128 (same proven pattern as FFN)
  #pragma unroll
  for (int it=0; it<4; ++it){
    int rbase = wave*16 + it*4;
    int r = rbase + lr;
    int oct = (d & 8) | ((d & 7) ^ (r & 7));
    int gr = bm + r; if (gr >= Nrows) gr = Nrows-1;
    gload16(A + (size_t)gr*128 + oct*8, As + rbase*128);
  }

  for (int t=0; t<4; ++t){
    int bn = t*128;
    if (t) __syncthreads();       // prior tile's Bs reads complete
    // stage Bs 128x128
    #pragma unroll
    for (int it=0; it<8; ++it){
      int rbase = wave*32 + it*4;
      int r = rbase + lr;
      int oct = (d & 8) | ((d & 7) ^ (r & 7));
      gload16(Bt + (size_t)(bn + r)*128 + oct*8, Bs + rbase*128);
    }
    __syncthreads();

    f32x4 zero = {0.f,0.f,0.f,0.f};
    f32x4 acc[2][4];
    #pragma unroll
    for (int m=0;m<2;m++)
      #pragma unroll
      for (int n=0;n<4;n++) acc[m][n] = zero;

    #pragma unroll
    for (int ks=0; ks<4; ++ks){
      int oi = ks*4 + lr;
      bf16x8 af[2], bfv[4];
      #pragma unroll
      for (int m=0;m<2;m++){
        int row = wr*32 + m*16 + d;
        int slot = (oi&8) | ((oi&7) ^ (row&7));
        af[m] = *(const bf16x8*)(As + row*128 + slot*8);
      }
      #pragma unroll
      for (int n=0;n<4;n++){
        int cn = wc*64 + n*16 + d;
        int slot = (oi&8) | ((oi&7) ^ (cn&7));
        bfv[n] = *(const bf16x8*)(Bs + cn*128 + slot*8);
      }
      #pragma unroll
      for (int m=0;m<2;m++)
        #pragma unroll
        for (int n=0;n<4;n++)
          acc[m][n] = __builtin_amdgcn_mfma_f32_16x16x32_bf16(af[m], bfv[n], acc[m][n], 0, 0, 0);
    }

    // remap: col<128 -> qx+col; col in [128,384) -> kv+(col-128); col>=384 -> qx+(col-256)
    short* dst; int coff;
    if (bn == 0)       { dst = qx; coff = 0;    }
    else if (bn < 384) { dst = kv; coff = -128; }
    else               { dst = qx; coff = -256; }

    #pragma unroll
    for (int m=0;m<2;m++){
      #pragma unroll
      for (int n=0;n<4;n++){
        int col = bn + wc*64 + n*16 + d;
        float bval = bias[col];
        #pragma unroll
        for (int j=0;j<4;j++){
          int row = bm + wr*32 + m*16 + lr*4 + j;
          if (row < Nrows){
            float v = acc[m][n][j] + bval;
            dst[(size_t)row*256 + col + coff] = f2b(v);
          }
        }
      }
    }
  }
}

// ---------------- fused FFN: relu(A@W1t^T+b1)@W2t^T + b2 + residual + LN2 ----------------
__global__ __launch_bounds__(256) void gemm_ffn_ln(
    const short* __restrict__ W1t,  // bf16 [512][128]
    const short* __restrict__ W2t,  // bf16 [128][512]
    const float* __restrict__ bias1,
    const float* __restrict__ bias2,
    short* __restrict__ hb,         // bf16 [N][128]: input A, residual, and output
    const float* __restrict__ g, const float* __restrict__ b,
    int Nrows)
{
  __shared__ short As[64*128];    // 16KB
  __shared__ short Bs[128*128];   // 32KB (current W1 chunk)
  __shared__ short F1[64*128];    // 16KB (ff1 tile, swizzled)
  __shared__ float red[2][64][2]; // 1KB
  int tid  = threadIdx.x;
  int lane = tid & 63;
  int wave = tid >> 6;
  int wr = wave >> 1, wc = wave & 1;
  int bm = blockIdx.x * 64;
  int d  = lane & 15;
  int lr = lane >> 4;

  #pragma unroll
  for (int it=0; it<4; ++it){
    int rbase = wave*16 + it*4;
    int r = rbase + lr;
    int oct = (d & 8) | ((d & 7) ^ (r & 7));
    int gr = bm + r; if (gr >= Nrows) gr = Nrows-1;
    gload16(hb + (size_t)gr*128 + oct*8, As + rbase*128);
  }

  f32x4 zero = {0.f,0.f,0.f,0.f};
  f32x4 acc2[2][4];
  #pragma unroll
  for (int m=0;m<2;m++)
    #pragma unroll
    for (int n=0;n<4;n++) acc2[m][n] = zero;

  for (int t=0; t<4; ++t){
    #pragma unroll
    for (int it=0; it<8; ++it){
      int rbase = wave*32 + it*4;
      int r = rbase + lr;
      int oct = (d & 8) | ((d & 7) ^ (r & 7));
      gload16(W1t + (size_t)(t*128 + r)*128 + oct*8, Bs + rbase*128);
    }
    __syncthreads();

    f32x4 acc1[2][4];
    #pragma unroll
    for (int m=0;m<2;m++)
      #pragma unroll
      for (int n=0;n<4;n++) acc1[m][n] = zero;
    #pragma unroll
    for (int ks=0; ks<4; ++ks){
      int oi = ks*4 + lr;
      bf16x8 af[2], bfv[4];
      #pragma unroll
      for (int m=0;m<2;m++){
        int row = wr*32 + m*16 + d;
        int slot = (oi&8) | ((oi&7) ^ (row&7));
        af[m] = *(const bf16x8*)(As + row*128 + slot*8);
      }
      #pragma unroll
      for (int n=0;n<4;n++){
        int cn = wc*64 + n*16 + d;
        int slot = (oi&8) | ((oi&7) ^ (cn&7));
        bfv[n] = *(const bf16x8*)(Bs + cn*128 + slot*8);
      }
      #pragma unroll
      for (int m=0;m<2;m++)
        #pragma unroll
        for (int n=0;n<4;n++)
          acc1[m][n] = __builtin_amdgcn_mfma_f32_16x16x32_bf16(af[m], bfv[n], acc1[m][n], 0, 0, 0);
    }
    __syncthreads();

    #pragma unroll
    for (int m=0;m<2;m++){
      #pragma unroll
      for (int n=0;n<4;n++){
        int col = wc*64 + n*16 + d;
        float bv1 = bias1[t*128 + col];
        int oct2 = col >> 3, within = col & 7;
        #pragma unroll
        for (int j=0;j<4;j++){
          int row = wr*32 + m*16 + lr*4 + j;
          float v = fmaxf(acc1[m][n][j] + bv1, 0.f);
          int so = (oct2 & 8) | ((oct2 & 7) ^ (row & 7));
          F1[row*128 + so*8 + within] = f2b(v);
        }
      }
    }
    __syncthreads();

    #pragma unroll
    for (int ks=0; ks<4; ++ks){
      int oi = ks*4 + lr;
      bf16x8 af[2], bfv[4];
      #pragma unroll
      for (int m=0;m<2;m++){
        int row = wr*32 + m*16 + d;
        int slot = (oi&8) | ((oi&7) ^ (row&7));
        af[m] = *(const bf16x8*)(F1 + row*128 + slot*8);
      }
      #pragma unroll
      for (int n=0;n<4;n++){
        int col = wc*64 + n*16 + d;
        bfv[n] = *(const bf16x8*)(W2t + (size_t)col*512 + t*128 + oi*8);
      }
      #pragma unroll
      for (int m=0;m<2;m++)
        #pragma unroll
        for (int n=0;n<4;n++)
          acc2[m][n] = __builtin_amdgcn_mfma_f32_16x16x32_bf16(af[m], bfv[n], acc2[m][n], 0, 0, 0);
    }
  }

  #pragma unroll
  for (int m=0;m<2;m++){
    #pragma unroll
    for (int n=0;n<4;n++){
      int col = wc*64 + n*16 + d;
      float bval = bias2[col];
      #pragma unroll
      for (int j=0;j<4;j++){
        int row = wr*32 + m*16 + lr*4 + j;
        int grow = bm + row; if (grow >= Nrows) grow = Nrows-1;
        acc2[m][n][j] += bval + b2f_s(hb[(size_t)grow*DIM + col]);
      }
    }
  }
  #pragma unroll
  for (int m=0;m<2;m++){
    #pragma unroll
    for (int j=0;j<4;j++){
      float ps = 0.f, pq = 0.f;
      #pragma unroll
      for (int n=0;n<4;n++){ float v = acc2[m][n][j]; ps += v; pq += v*v; }
      #pragma unroll
      for (int msk=1; msk<16; msk<<=1){ ps += __shfl_xor(ps, msk); pq += __shfl_xor(pq, msk); }
      if (d == 0){
        int row = wr*32 + m*16 + lr*4 + j;
        red[wc][row][0] = ps;
        red[wc][row][1] = pq;
      }
    }
  }
  __syncthreads();
  #pragma unroll
  for (int m=0;m<2;m++){
    #pragma unroll
    for (int j=0;j<4;j++){
      int row = wr*32 + m*16 + lr*4 + j;
      float S = red[0][row][0] + red[1][row][0];
      float Q = red[0][row][1] + red[1][row][1];
      float mu  = S*(1.f/128.f);
      float var = fmaxf(Q*(1.f/128.f) - mu*mu, 0.f);
      float rr  = rsqrtf(var + 1e-5f);
      int grow = bm + row;
      if (grow < Nrows){
        #pragma unroll
        for (int n=0;n<4;n++){
          int col = wc*64 + n*16 + d;
          float o = (acc2[m][n][j]-mu)*rr*g[col] + b[col];
          hb[(size_t)grow*DIM + col] = f2b(o);
        }
      }
    }
  }
}

// ---------------- fused edge attention + beta gate + LN1 ----------------
// 16 lanes per dst node, 8 ch/lane, degree-DESCENDING order, 2-edge unroll,
// src-index software pipeline, compact kv[N][256] gather array.
__global__ __launch_bounds__(256) void edge_attn_fused(
  const short* __restrict__ kv,       // bf16 [N][256]: k|v
  const short* __restrict__ qx,       // bf16 [N][256]: q|xr
  const short* __restrict__ ea_s, const int* __restrict__ src_s,
  const float* __restrict__ Wel, const float* __restrict__ bel,
  const int* __restrict__ row_start, const int* __restrict__ perm,
  short* __restrict__ hb,
  const float* __restrict__ Wb, const float* __restrict__ g, const float* __restrict__ b)
{
  int wid = (blockIdx.x*256 + threadIdx.x) >> 4;
  if (wid >= N_NODES) return;
  int node = perm[N_NODES - 1 - wid];   // highest degree first
  int ln = threadIdx.x & 15;
  int c0 = ln*8;

  const short* qrow = qx + (size_t)node*256;
  uint4 qu = *(const uint4*)(qrow + c0);
  float q0=b2f_lo(qu.x), q1=b2f_hi(qu.x), q2=b2f_lo(qu.y), q3=b2f_hi(qu.y);
  float q4=b2f_lo(qu.z), q5=b2f_hi(qu.z), q6=b2f_lo(qu.w), q7=b2f_hi(qu.w);

  float u[12];
  #pragma unroll
  for (int j=0;j<12;j++){
    float4 wA = *(const float4*)(Wel + j*DIM + c0);
    float4 wB = *(const float4*)(Wel + j*DIM + c0 + 4);
    float pp = q0*wA.x+q1*wA.y+q2*wA.z+q3*wA.w
             + q4*wB.x+q5*wB.y+q6*wB.z+q7*wB.w;
    u[j] = pp + __shfl_xor(pp,1);
  }
  float4 beA = *(const float4*)(bel + c0);
  float4 beB = *(const float4*)(bel + c0 + 4);
  float qbe;
  { float pp = q0*beA.x+q1*beA.y+q2*beA.z+q3*beA.w
             + q4*beB.x+q5*beB.y+q6*beB.z+q7*beB.w;
    qbe = pp + __shfl_xor(pp,1); }

  int rs = row_start[node], re = row_start[node+1];
  float den = 0.f;
  float av[8] = {0.f,0.f,0.f,0.f,0.f,0.f,0.f,0.f};
  float aEA[12] = {0.f,0.f,0.f,0.f,0.f,0.f,0.f,0.f,0.f,0.f,0.f,0.f};

  int npairs = (re - rs) >> 1;
  int s0 = 0, s1 = 0;
  if (npairs > 0){ s0 = src_s[rs]; s1 = src_s[rs+1]; }
  for (int p=0; p<npairs; ++p){
    int i = rs + p*2;
    int s0n = 0, s1n = 0;
    if (p+1 < npairs){ s0n = src_s[i+2]; s1n = src_s[i+3]; }
    const short* e0p = ea_s + (size_t)i*EDIM;
    uint2 a00 = *(const uint2*)(e0p);
    uint2 a01 = *(const uint2*)(e0p+4);
    uint2 a02 = *(const uint2*)(e0p+8);
    uint2 a10 = *(const uint2*)(e0p+12);
    uint2 a11 = *(const uint2*)(e0p+16);
    uint2 a12 = *(const uint2*)(e0p+20);
    const short* r0p = kv + (size_t)s0*256;
    const short* r1p = kv + (size_t)s1*256;
    uint4 ku0 = *(const uint4*)(r0p + c0);
    uint4 vu0 = *(const uint4*)(r0p + 128 + c0);
    uint4 ku1 = *(const uint4*)(r1p + c0);
    uint4 vu1 = *(const uint4*)(r1p + 128 + c0);

    float ea0[12], ea1[12];
    ea0[0]=b2f_lo(a00.x); ea0[1]=b2f_hi(a00.x); ea0[2]=b2f_lo(a00.y); ea0[3]=b2f_hi(a00.y);
    ea0[4]=b2f_lo(a01.x); ea0[5]=b2f_hi(a01.x); ea0[6]=b2f_lo(a01.y); ea0[7]=b2f_hi(a01.y);
    ea0[8]=b2f_lo(a02.x); ea0[9]=b2f_hi(a02.x); ea0[10]=b2f_lo(a02.y); ea0[11]=b2f_hi(a02.y);
    ea1[0]=b2f_lo(a10.x); ea1[1]=b2f_hi(a10.x); ea1[2]=b2f_lo(a10.y); ea1[3]=b2f_hi(a10.y);
    ea1[4]=b2f_lo(a11.x); ea1[5]=b2f_hi(a11.x); ea1[6]=b2f_lo(a11.y); ea1[7]=b2f_hi(a11.y);
    ea1[8]=b2f_lo(a12.x); ea1[9]=b2f_hi(a12.x); ea1[10]=b2f_lo(a12.y); ea1[11]=b2f_hi(a12.y);

    float pp0 = q0*b2f_lo(ku0.x) + q1*b2f_hi(ku0.x) + q2*b2f_lo(ku0.y) + q3*b2f_hi(ku0.y)
              + q4*b2f_lo(ku0.z) + q5*b2f_hi(ku0.z) + q6*b2f_lo(ku0.w) + q7*b2f_hi(ku0.w);
    float pp1 = q0*b2f_lo(ku1.x) + q1*b2f_hi(ku1.x) + q2*b2f_lo(ku1.y) + q3*b2f_hi(ku1.y)
              + q4*b2f_lo(ku1.z) + q5*b2f_hi(ku1.z) + q6*b2f_lo(ku1.w) + q7*b2f_hi(ku1.w);
    float al0 = pp0 + __shfl_xor(pp0,1) + qbe;
    float al1 = pp1 + __shfl_xor(pp1,1) + qbe;
    #pragma unroll
    for (int j=0;j<12;j++){ al0 += ea0[j]*u[j]; al1 += ea1[j]*u[j]; }
    float p0 = __expf(al0 * ASCALE);
    float p1 = __expf(al1 * ASCALE);
    den += p0 + p1;
    av[0] += p0*b2f_lo(vu0.x) + p1*b2f_lo(vu1.x);
    av[1] += p0*b2f_hi(vu0.x) + p1*b2f_hi(vu1.x);
    av[2] += p0*b2f_lo(vu0.y) + p1*b2f_lo(vu1.y);
    av[3] += p0*b2f_hi(vu0.y) + p1*b2f_hi(vu1.y);
    av[4] += p0*b2f_lo(vu0.z) + p1*b2f_lo(vu1.z);
    av[5] += p0*b2f_hi(vu0.z) + p1*b2f_hi(vu1.z);
    av[6] += p0*b2f_lo(vu0.w) + p1*b2f_lo(vu1.w);
    av[7] += p0*b2f_hi(vu0.w) + p1*b2f_hi(vu1.w);
    #pragma unroll
    for (int j=0;j<12;j++) aEA[j] += p0*ea0[j] + p1*ea1[j];
    s0 = s0n; s1 = s1n;
  }
  {
    int i = rs + npairs*2;
    if (i < re){
      int s = src_s[i];
      const short* eap = ea_s + (size_t)i*EDIM;
      uint2 eu0 = *(const uint2*)(eap);
      uint2 eu1 = *(const uint2*)(eap+4);
      uint2 eu2 = *(const uint2*)(eap+8);
      float ea0[12];
      ea0[0]=b2f_lo(eu0.x); ea0[1]=b2f_hi(eu0.x); ea0[2]=b2f_lo(eu0.y); ea0[3]=b2f_hi(eu0.y);
      ea0[4]=b2f_lo(eu1.x); ea0[5]=b2f_hi(eu1.x); ea0[6]=b2f_lo(eu1.y); ea0[7]=b2f_hi(eu1.y);
      ea0[8]=b2f_lo(eu2.x); ea0[9]=b2f_hi(eu2.x); ea0[10]=b2f_lo(eu2.y); ea0[11]=b2f_hi(eu2.y);
      const short* srow = kv + (size_t)s*256;
      uint4 ku = *(const uint4*)(srow + c0);
      uint4 vu = *(const uint4*)(srow + 128 + c0);
      float pp = q0*b2f_lo(ku.x) + q1*b2f_hi(ku.x) + q2*b2f_lo(ku.y) + q3*b2f_hi(ku.y)
               + q4*b2f_lo(ku.z) + q5*b2f_hi(ku.z) + q6*b2f_lo(ku.w) + q7*b2f_hi(ku.w);
      float alpha = pp + __shfl_xor(pp,1) + qbe;
      #pragma unroll
      for (int j=0;j<12;j++) alpha += ea0[j]*u[j];
      float p = __expf(alpha * ASCALE);
      den += p;
      av[0] += p*b2f_lo(vu.x); av[1] += p*b2f_hi(vu.x);
      av[2] += p*b2f_lo(vu.y); av[3] += p*b2f_hi(vu.y);
      av[4] += p*b2f_lo(vu.z); av[5] += p*b2f_hi(vu.z);
      av[6] += p*b2f_lo(vu.w); av[7] += p*b2f_hi(vu.w);
      #pragma unroll
      for (int j=0;j<12;j++) aEA[j] += p*ea0[j];
    }
  }

  float inv = 1.f/(den + 1e-16f);
  float gg[8];
  #pragma unroll
  for (int c=0;c<8;c++) gg[c] = av[c]*inv;
  #pragma unroll
  for (int j=0;j<12;j++){
    float wgt = aEA[j]*inv;
    float4 wA = *(const float4*)(Wel + j*DIM + c0);
    float4 wB = *(const float4*)(Wel + j*DIM + c0 + 4);
    gg[0]+=wgt*wA.x; gg[1]+=wgt*wA.y; gg[2]+=wgt*wA.z; gg[3]+=wgt*wA.w;
    gg[4]+=wgt*wB.x; gg[5]+=wgt*wB.y; gg[6]+=wgt*wB.z; gg[7]+=wgt*wB.w;
  }
  if (re > rs){
    gg[0]+=beA.x; gg[1]+=beA.y; gg[2]+=beA.z; gg[3]+=beA.w;
    gg[4]+=beB.x; gg[5]+=beB.y; gg[6]+=beB.z; gg[7]+=beB.w;
  }

  // beta gate (residual from bf16 hb)
  uint4 xu = *(const uint4*)(qrow + 128 + c0);
  float x[8];
  x[0]=b2f_lo(xu.x); x[1]=b2f_hi(xu.x); x[2]=b2f_lo(xu.y); x[3]=b2f_hi(xu.y);
  x[4]=b2f_lo(xu.z); x[5]=b2f_hi(xu.z); x[6]=b2f_lo(xu.w); x[7]=b2f_hi(xu.w);
  uint4 hu = *(const uint4*)(hb + (size_t)node*DIM + c0);
  float hv[8];
  unp8(hu, hv);
  float4 waA = *(const float4*)(Wb + c0),       waB = *(const float4*)(Wb + c0 + 4);
  float4 wxA = *(const float4*)(Wb + DIM + c0), wxB = *(const float4*)(Wb + DIM + c0 + 4);
  float4 wdA = *(const float4*)(Wb + 2*DIM + c0), wdB = *(const float4*)(Wb + 2*DIM + c0 + 4);
  float wa[8] = {waA.x,waA.y,waA.z,waA.w,waB.x,waB.y,waB.z,waB.w};
  float wx[8] = {wxA.x,wxA.y,wxA.z,wxA.w,wxB.x,wxB.y,wxB.z,wxB.w};
  float wd[8] = {wdA.x,wdA.y,wdA.z,wdA.w,wdB.x,wdB.y,wdB.z,wdB.w};
  float sacc = 0.f;
  #pragma unroll
  for (int c=0;c<8;c++) sacc += gg[c]*wa[c] + x[c]*wx[c] + (gg[c]-x[c])*wd[c];
  sacc = sum16(sacc);
  float beta = 1.f/(1.f + __expf(-sacc));
  float t[8], ts = 0.f;
  #pragma unroll
  for (int c=0;c<8;c++){ t[c] = beta*x[c] + (1.f-beta)*gg[c] + hv[c]; ts += t[c]; }
  float mu = sum16(ts)*(1.f/128.f);
  float vs = 0.f;
  #pragma unroll
  for (int c=0;c<8;c++){ t[c] -= mu; vs += t[c]*t[c]; }
  float var = sum16(vs)*(1.f/128.f);
  float r = rsqrtf(var + 1e-5f);
  float4 gA = *(const float4*)(g + c0), gB = *(const float4*)(g + c0 + 4);
  float4 bA = *(const float4*)(b + c0), bB = *(const float4*)(b + c0 + 4);
  float gv[8] = {gA.x,gA.y,gA.z,gA.w,gB.x,gB.y,gB.z,gB.w};
  float bv[8] = {bA.x,bA.y,bA.z,bA.w,bB.x,bB.y,bB.z,bB.w};
  float o[8];
  #pragma unroll
  for (int c=0;c<8;c++) o[c] = t[c]*r*gv[c] + bv[c];
  uint4 ou;
  ou.x = (unsigned int)(unsigned short)f2b(o[0]) | ((unsigned int)(unsigned short)f2b(o[1])<<16);
  ou.y = (unsigned int)(unsigned short)f2b(o[2]) | ((unsigned int)(unsigned short)f2b(o[3])<<16);
  ou.z = (unsigned int)(unsigned short)f2b(o[4]) | ((unsigned int)(unsigned short)f2b(o[5])<<16);
  ou.w = (unsigned int)(unsigned short)f2b(o[6]) | ((unsigned int)(unsigned short)f2b(o[7])<<16);
  *(uint4*)(hb + (size_t)node*DIM + c0) = ou;
}

// ---------------- segmented mean pool + output projection (256 threads) ----------------
__global__ __launch_bounds__(256) void pool_out(
  const short* __restrict__ hb, const int* __restrict__ batch,
  const float* __restrict__ Wout, const float* __restrict__ bout,
  float* __restrict__ out)
{
  int bidx = blockIdx.x;
  int d = threadIdx.x & 127;
  int half = threadIdx.x >> 7;
  __shared__ int seg[2];
  __shared__ float psum[2][DIM];
  __shared__ float p[DIM];
  if (threadIdx.x < 2){
    int target = bidx + threadIdx.x;
    int lo = 0, hi = N_NODES;
    while (lo < hi){ int mid = (lo+hi)>>1; if (batch[mid] < target) lo = mid+1; else hi = mid; }
    seg[threadIdx.x] = lo;
  }
  __syncthreads();
  int lo = seg[0], hi = seg[1];
  float s = 0.f;
  for (int n=lo+half; n<hi; n+=2) s += b2f_s(hb[(size_t)n*DIM + d]);
  psum[half][d] = s;
  __syncthreads();
  if (half == 0){
    float cnt = (float)(hi - lo);
    p[d] = (psum[0][d] + psum[1][d]) / fmaxf(cnt, 1.f);
  }
  __syncthreads();
  float o = 0.f;
  #pragma unroll 8
  for (int kk=half*64; kk<half*64+64; ++kk) o += p[kk]*Wout[kk*DIM + d];
  psum[half][d] = o;
  __syncthreads();
  if (half == 0) out[bidx*DIM + d] = psum[0][d] + psum[1][d] + bout[d];
}

extern "C" void kernel_launch(void* const* d_in, const int* in_sizes, int n_in,
                              void* d_out, int out_size, void* d_ws, size_t ws_size,
                              hipStream_t stream)
{
  const float* x     = (const float*)d_in[0];
  const float* ea    = (const float*)d_in[1];
  const int*   ei    = (const int*)d_in[2];
  const int*   batch = (const int*)d_in[3];
  const float* Wemb  = (const float*)d_in[4];
  const float* bemb  = (const float*)d_in[5];
  const float* Wout  = (const float*)d_in[6];
  const float* bout  = (const float*)d_in[7];
  const float* Wq    = (const float*)d_in[8];
  const float* bq    = (const float*)d_in[9];
  const float* Wk    = (const float*)d_in[10];
  const float* bk    = (const float*)d_in[11];
  const float* Wv    = (const float*)d_in[12];
  const float* bv    = (const float*)d_in[13];
  const float* We    = (const float*)d_in[14];
  const float* be    = (const float*)d_in[15];
  const float* Wskip = (const float*)d_in[16];
  const float* bskip = (const float*)d_in[17];
  const float* Wbeta = (const float*)d_in[18];
  const float* g1    = (const float*)d_in[19];
  const float* b1    = (const float*)d_in[20];
  const float* g2    = (const float*)d_in[21];
  const float* b2    = (const float*)d_in[22];
  const float* Wf1   = (const float*)d_in[23];
  const float* bf1   = (const float*)d_in[24];
  const float* Wf2   = (const float*)d_in[25];
  const float* bf2   = (const float*)d_in[26];
  float* out = (float*)d_out;

  // ---- workspace layout ----
  float* ws     = (float*)d_ws;
  float* bqkvs  = ws;                                  // L*512
  short* ea_s   = (short*)(bqkvs + LAYERS*512);        // E*12 (bf16)
  short* hb     = ea_s + (size_t)N_EDGES*EDIM;         // N*128
  short* kv     = hb + (size_t)N_NODES*DIM;            // N*256 (k|v, gather hot set)
  short* qx     = kv + (size_t)N_NODES*256;            // N*256 (q|xr)
  short* xb     = qx + (size_t)N_NODES*256;            // N*128
  short* wemb_t = xb + (size_t)N_NODES*DIM;            // 128*128
  short* wq_t   = wemb_t + DIM*DIM;                    // L*512*128
  short* wf1_t  = wq_t  + (size_t)LAYERS*NDFF*DIM;
  short* wf2_t  = wf1_t + (size_t)LAYERS*NDFF*DIM;
  int*   cnt       = (int*)(wf2_t + (size_t)LAYERS*NDFF*DIM);
  int*   cnt2      = cnt + N_NODES;
  int*   row_start = cnt2 + N_NODES;                   // N+1
  int*   bsum      = row_start + N_NODES + 1;          // 64
  int*   dhist     = bsum + 64;                        // 256
  int*   dcnt      = dhist + 256;                      // 256
  int*   dstart    = dcnt + 256;                       // 256
  int*   node_perm = dstart + 256;                     // N
  int*   src_s     = node_perm + N_NODES;              // E

  hipMemsetAsync(cnt,  0, N_NODES*sizeof(int), stream);
  hipMemsetAsync(cnt2, 0, N_NODES*sizeof(int), stream);
  hipMemsetAsync(dhist, 0, 512*sizeof(int), stream);   // dhist + dcnt

  const int NB_SCAN = (N_NODES + 1023)/1024;           // 49
  const int NB_DEG  = (N_NODES + 255)/256;             // 196
  count_kernel<<<(N_EDGES+255)/256, 256, 0, stream>>>(ei, cnt);
  scan1<<<NB_SCAN, 1024, 0, stream>>>(cnt, row_start, bsum);
  scan2<<<1, 64, 0, stream>>>(bsum, NB_SCAN);
  scan3<<<(N_NODES+255)/256, 256, 0, stream>>>(row_start, bsum);
  deg_hist<<<NB_DEG, 256, 0, stream>>>(cnt, dhist);
  deg_scan<<<1, 256, 0, stream>>>(dhist, dstart);
  deg_place<<<NB_DEG, 256, 0, stream>>>(cnt, dcnt, dstart, node_perm);
  scatter_kernel<<<(N_EDGES+255)/256, 256, 0, stream>>>(ei, ea, cnt2, row_start, src_s, ea_s);

  pack_weights<<<dim3(768, LAYERS), 256, 0, stream>>>(
      Wq, Wk, Wv, Wskip, bq, bk, bv, bskip, Wf1, Wf2, wq_t, wf1_t, wf2_t, bqkvs);
  pack_emb<<<64, 256, 0, stream>>>(Wemb, wemb_t);
  cast_pad_x<<<(N_NODES*64 + 255)/256, 256, 0, stream>>>(x, xb);

  int gM  = (N_NODES + 127)/128;                       // 391
  int gM64 = (N_NODES + 63)/64;                        // 782
  int attnBlocks = (N_NODES*16 + 255)/256;             // 3125

  // hb = bf16(x @ Wemb + bemb) via MFMA
  gemm_k128<<<dim3(gM, 1), 256, 0, stream>>>(xb, wemb_t, bemb, hb, N_NODES, DIM, 0, 1);

  for (int l=0; l<LAYERS; ++l){
    // fused Q|K|V|skip projection -> kv[N][256] + qx[N][256]  (64-row strips)
    gemm_qkvs<<<dim3(gM64, 1), 256, 0, stream>>>(
        hb, wq_t + (size_t)l*NDFF*DIM, bqkvs + l*512, kv, qx, N_NODES);

    // attention + beta gate + LN1 -> hb
    edge_attn_fused<<<attnBlocks, 256, 0, stream>>>(
        kv, qx, ea_s, src_s, We + (size_t)l*EDIM*DIM, be + l*DIM, row_start, node_perm,
        hb, Wbeta + l*3*DIM, g1 + l*DIM, b1 + l*DIM);

    // fused FF1+FF2 + residual + LN2 -> hb  (ff1 never touches HBM)
    gemm_ffn_ln<<<dim3(gM64, 1), 256, 0, stream>>>(
        wf1_t + (size_t)l*NDFF*DIM, wf2_t + (size_t)l*DIM*NDFF,
        bf1 + l*NDFF, bf2 + l*DIM, hb,
        g2 + l*DIM, b2 + l*DIM, N_NODES);
  }

  pool_out<<<NBATCH, 256, 0, stream>>>(hb, batch, Wout, bout, out);
}

// Round 15
// 750.544 us; speedup vs baseline: 1.0240x; 1.0240x over previous
//
#include <hip/hip_runtime.h>
#include <math.h>

#define N_NODES 50000
#define N_EDGES 600000
#define FATOM   78
#define DIM     128
#define HEADS   8
#define EDIM    12
#define LAYERS  4
#define NBATCH  512
#define NDFF    512
#define ASCALE  0.25f   // 1/sqrt(16)

typedef __attribute__((ext_vector_type(8))) short bf16x8;
typedef __attribute__((ext_vector_type(4))) float f32x4;

__device__ __forceinline__ float sum16(float v){
  #pragma unroll
  for (int m=1;m<16;m<<=1) v += __shfl_xor(v, m);
  return v;
}
__device__ __forceinline__ short f2b(float f){
  unsigned int u = __builtin_bit_cast(unsigned int, f);
  u += 0x7fffu + ((u>>16)&1u);
  return (short)(u>>16);
}
__device__ __forceinline__ float b2f_lo(unsigned int u){ return __builtin_bit_cast(float, u<<16); }
__device__ __forceinline__ float b2f_hi(unsigned int u){ return __builtin_bit_cast(float, u & 0xffff0000u); }
__device__ __forceinline__ float b2f_s(short s){
  return __builtin_bit_cast(float, ((unsigned int)(unsigned short)s)<<16);
}
__device__ __forceinline__ void unp8(uint4 u, float* o){
  o[0]=b2f_lo(u.x); o[1]=b2f_hi(u.x); o[2]=b2f_lo(u.y); o[3]=b2f_hi(u.y);
  o[4]=b2f_lo(u.z); o[5]=b2f_hi(u.z); o[6]=b2f_lo(u.w); o[7]=b2f_hi(u.w);
}

__device__ __forceinline__ void gload16(const short* g, short* l){
  __builtin_amdgcn_global_load_lds(
      (const __attribute__((address_space(1))) void*)g,
      (__attribute__((address_space(3))) void*)l, 16, 0, 0);
}

// ---------------- CSR build ----------------
__global__ void count_kernel(const int* __restrict__ ei, int* __restrict__ cnt){
  int e = blockIdx.x*256 + threadIdx.x;
  if (e < N_EDGES) atomicAdd(&cnt[ei[N_EDGES + e]], 1);
}

__global__ __launch_bounds__(1024) void scan1(const int* __restrict__ cnt,
                                              int* __restrict__ row_start, int* __restrict__ bsum){
  __shared__ int lds[1024];
  int gid = blockIdx.x*1024 + threadIdx.x;
  int v = (gid < N_NODES) ? cnt[gid] : 0;
  lds[threadIdx.x] = v; __syncthreads();
  for (int off=1; off<1024; off<<=1){
    int add = (threadIdx.x>=off)?lds[threadIdx.x-off]:0;
    __syncthreads();
    lds[threadIdx.x]+=add;
    __syncthreads();
  }
  if (gid < N_NODES) row_start[gid+1] = lds[threadIdx.x];
  if (threadIdx.x==1023) bsum[blockIdx.x] = lds[1023];
}
__global__ void scan2(int* __restrict__ bsum, int nb){
  int tid = threadIdx.x;
  int v = (tid < nb) ? bsum[tid] : 0;
  #pragma unroll
  for (int off=1; off<64; off<<=1){
    int u = __shfl_up(v, off);
    if (tid >= off) v += u;
  }
  if (tid < nb) bsum[tid] = v;   // inclusive
}
__global__ void scan3(int* __restrict__ row_start, const int* __restrict__ bsum){
  int gid = blockIdx.x*256 + threadIdx.x;
  if (gid == 0) row_start[0] = 0;
  if (gid < N_NODES){
    int blk = gid >> 10;
    if (blk > 0) row_start[gid+1] += bsum[blk-1];
  }
}

// edges into dst-CSR order; src id + bf16 edge_attr gathered into sorted order
__global__ void scatter_kernel(const int* __restrict__ ei, const float* __restrict__ ea,
                               int* __restrict__ cnt2, const int* __restrict__ row_start,
                               int* __restrict__ src_s, short* __restrict__ ea_s){
  int e = blockIdx.x*256 + threadIdx.x;
  if (e < N_EDGES){
    int d = ei[N_EDGES + e];
    int pos = atomicAdd(&cnt2[d], 1);
    int p = row_start[d] + pos;
    src_s[p] = ei[e];
    const float* src = ea + (size_t)e*EDIM;
    unsigned int* dst = (unsigned int*)(ea_s + (size_t)p*EDIM);
    #pragma unroll
    for (int j=0;j<6;j++){
      unsigned int lo = (unsigned int)(unsigned short)f2b(src[2*j]);
      unsigned int hi = (unsigned int)(unsigned short)f2b(src[2*j+1]);
      dst[j] = lo | (hi<<16);
    }
  }
}

// ---------------- degree sort (block-aggregated counting sort) ----------------
__global__ __launch_bounds__(256) void deg_hist(const int* __restrict__ cnt, int* __restrict__ dhist){
  __shared__ int lh[256];
  lh[threadIdx.x] = 0; __syncthreads();
  int n = blockIdx.x*256 + threadIdx.x;
  if (n < N_NODES){
    int d = cnt[n]; if (d > 255) d = 255;
    atomicAdd(&lh[d], 1);
  }
  __syncthreads();
  int c = lh[threadIdx.x];
  if (c) atomicAdd(&dhist[threadIdx.x], c);
}
__global__ __launch_bounds__(256) void deg_scan(const int* __restrict__ dhist, int* __restrict__ dstart){
  __shared__ int l[256];
  int t = threadIdx.x;
  int v = dhist[t];
  l[t] = v; __syncthreads();
  for (int off=1; off<256; off<<=1){
    int add = (t>=off)? l[t-off]:0;
    __syncthreads();
    l[t]+=add;
    __syncthreads();
  }
  dstart[t] = l[t]-v;   // exclusive
}
__global__ __launch_bounds__(256) void deg_place(const int* __restrict__ cnt, int* __restrict__ dcnt,
                                                 const int* __restrict__ dstart, int* __restrict__ perm){
  __shared__ int lh[256];
  __shared__ int lbase[256];
  __shared__ int lrank[256];
  int t = threadIdx.x;
  lh[t] = 0; lrank[t] = 0; __syncthreads();
  int n = blockIdx.x*256 + t;
  int d = -1;
  if (n < N_NODES){
    d = cnt[n]; if (d > 255) d = 255;
    atomicAdd(&lh[d], 1);
  }
  __syncthreads();
  int c = lh[t];
  lbase[t] = c ? atomicAdd(&dcnt[t], c) : 0;
  __syncthreads();
  if (n < N_NODES){
    int r = atomicAdd(&lrank[d], 1);
    perm[dstart[d] + lbase[d] + r] = n;
  }
}

// ---------------- weight packing: transpose to [M][K] bf16 ----------------
__global__ __launch_bounds__(256) void pack_weights(
  const float* __restrict__ Wq, const float* __restrict__ Wk,
  const float* __restrict__ Wv, const float* __restrict__ Ws,
  const float* __restrict__ bq, const float* __restrict__ bk,
  const float* __restrict__ bv, const float* __restrict__ bs,
  const float* __restrict__ Wf1, const float* __restrict__ Wf2,
  short* __restrict__ wq_t, short* __restrict__ wf1_t, short* __restrict__ wf2_t,
  float* __restrict__ bqkvs)
{
  int l = blockIdx.y;
  int idx = blockIdx.x*256 + threadIdx.x;   // 0 .. 3*65536-1
  int sec = idx >> 16, r = idx & 65535;
  if (sec == 0){
    int n = r >> 7, k = r & 127;
    const float* W = (n<128)?Wq:(n<256)?Wk:(n<384)?Wv:Ws;
    float v = W[(size_t)l*16384 + k*128 + (n&127)];
    wq_t[(size_t)l*65536 + n*128 + k] = f2b(v);
    if (k == 0){
      const float* bb = (n<128)?bq:(n<256)?bk:(n<384)?bv:bs;
      bqkvs[l*512 + n] = bb[l*128 + (n&127)];
    }
  } else if (sec == 1){
    int n = r >> 7, k = r & 127;
    wf1_t[(size_t)l*65536 + n*128 + k] = f2b(Wf1[(size_t)l*65536 + k*512 + n]);
  } else {
    int n = r >> 9, k = r & 511;
    wf2_t[(size_t)l*65536 + n*512 + k] = f2b(Wf2[(size_t)l*65536 + k*128 + n]);
  }
}

__global__ void pack_emb(const float* __restrict__ Wemb, short* __restrict__ wemb_t){
  int idx = blockIdx.x*256 + threadIdx.x;     // 128*128
  int nn = idx >> 7, k = idx & 127;
  wemb_t[nn*128 + k] = (k < FATOM) ? f2b(Wemb[(size_t)k*DIM + nn]) : (short)0;
}

__global__ void cast_pad_x(const float* __restrict__ x, short* __restrict__ xb){
  int idx = blockIdx.x*256 + threadIdx.x;     // N*64 u32-pairs
  int n = idx >> 6, kp = (idx & 63)*2;
  if (n >= N_NODES) return;
  float v0 = (kp   < FATOM) ? x[(size_t)n*FATOM + kp]   : 0.f;
  float v1 = (kp+1 < FATOM) ? x[(size_t)n*FATOM + kp+1] : 0.f;
  unsigned int lo = (unsigned int)(unsigned short)f2b(v0);
  unsigned int hi = (unsigned int)(unsigned short)f2b(v1);
  *(unsigned int*)(xb + (size_t)n*128 + kp) = lo | (hi<<16);
}

// ---------------- single-stage K=128 MFMA GEMM (generic, bf16 out) ----------------
__global__ __launch_bounds__(256) void gemm_k128(
    const short* __restrict__ A,   // bf16 [N][128]
    const short* __restrict__ Bt,  // bf16 [M][128]
    const float* __restrict__ bias,
    short* __restrict__ Cb,        // bf16 out
    int Nrows, int M, int relu, int nbn)
{
  __shared__ short As[128*128];
  __shared__ short Bs[128*128];
  int tid  = threadIdx.x;
  int lane = tid & 63;
  int wave = tid >> 6;
  int wr = wave >> 1, wc = wave & 1;
  int bm = blockIdx.x * 128;
  int d  = lane & 15;
  int lr = lane >> 4;

  #pragma unroll
  for (int it=0; it<8; ++it){
    int r = wave*32 + it*4 + lr;
    int oct = (d & 8) | ((d & 7) ^ (r & 7));
    int gr = bm + r; if (gr >= Nrows) gr = Nrows-1;
    gload16(A + (size_t)gr*128 + oct*8, As + (wave*32 + it*4)*128);
  }

  for (int t=0; t<nbn; ++t){
    int bn = (blockIdx.y*nbn + t)*128;
    if (t) __syncthreads();
    #pragma unroll
    for (int it=0; it<8; ++it){
      int r = wave*32 + it*4 + lr;
      int oct = (d & 8) | ((d & 7) ^ (r & 7));
      gload16(Bt + (size_t)(bn + r)*128 + oct*8, Bs + (wave*32 + it*4)*128);
    }
    f32x4 zero = {0.f,0.f,0.f,0.f};
    f32x4 acc[4][4];
    #pragma unroll
    for (int m=0;m<4;m++)
      #pragma unroll
      for (int n=0;n<4;n++) acc[m][n] = zero;

    __syncthreads();

    #pragma unroll
    for (int ks=0; ks<4; ++ks){
      int oi = ks*4 + lr;
      bf16x8 af[4], bfv[4];
      #pragma unroll
      for (int m=0;m<4;m++){
        int row = wr*64 + m*16 + d;
        int slot = (oi&8) | ((oi&7) ^ (row&7));
        af[m] = *(const bf16x8*)(As + row*128 + slot*8);
      }
      #pragma unroll
      for (int n=0;n<4;n++){
        int col = wc*64 + n*16 + d;
        int slot = (oi&8) | ((oi&7) ^ (col&7));
        bfv[n] = *(const bf16x8*)(Bs + col*128 + slot*8);
      }
      #pragma unroll
      for (int m=0;m<4;m++)
        #pragma unroll
        for (int n=0;n<4;n++)
          acc[m][n] = __builtin_amdgcn_mfma_f32_16x16x32_bf16(af[m], bfv[n], acc[m][n], 0, 0, 0);
    }

    #pragma unroll
    for (int m=0;m<4;m++){
      #pragma unroll
      for (int n=0;n<4;n++){
        int col = bn + wc*64 + n*16 + d;
        float bval = bias[col];
        #pragma unroll
        for (int j=0;j<4;j++){
          int row = bm + wr*64 + m*16 + lr*4 + j;
          if (row < Nrows){
            float v = acc[m][n][j] + bval;
            if (relu) v = fmaxf(v, 0.f);
            Cb[(size_t)row*M + col] = f2b(v);
          }
        }
      }
    }
  }
}

// ---------------- QKVS GEMM: writes kv[N][256]=k|v and qx[N][256]=q|xr ----------------
__global__ __launch_bounds__(256) void gemm_qkvs(
    const short* __restrict__ A,   // bf16 [N][128]
    const short* __restrict__ Bt,  // bf16 [512][128]
    const float* __restrict__ bias,
    short* __restrict__ kv, short* __restrict__ qx,
    int Nrows, int nbn)
{
  __shared__ short As[128*128];
  __shared__ short Bs[128*128];
  int tid  = threadIdx.x;
  int lane = tid & 63;
  int wave = tid >> 6;
  int wr = wave >> 1, wc = wave & 1;
  int bm = blockIdx.x * 128;
  int d  = lane & 15;
  int lr = lane >> 4;

  #pragma unroll
  for (int it=0; it<8; ++it){
    int r = wave*32 + it*4 + lr;
    int oct = (d & 8) | ((d & 7) ^ (r & 7));
    int gr = bm + r; if (gr >= Nrows) gr = Nrows-1;
    gload16(A + (size_t)gr*128 + oct*8, As + (wave*32 + it*4)*128);
  }

  for (int t=0; t<nbn; ++t){
    int bn = (blockIdx.y*nbn + t)*128;
    if (t) __syncthreads();
    #pragma unroll
    for (int it=0; it<8; ++it){
      int r = wave*32 + it*4 + lr;
      int oct = (d & 8) | ((d & 7) ^ (r & 7));
      gload16(Bt + (size_t)(bn + r)*128 + oct*8, Bs + (wave*32 + it*4)*128);
    }
    f32x4 zero = {0.f,0.f,0.f,0.f};
    f32x4 acc[4][4];
    #pragma unroll
    for (int m=0;m<4;m++)
      #pragma unroll
      for (int n=0;n<4;n++) acc[m][n] = zero;

    __syncthreads();

    #pragma unroll
    for (int ks=0; ks<4; ++ks){
      int oi = ks*4 + lr;
      bf16x8 af[4], bfv[4];
      #pragma unroll
      for (int m=0;m<4;m++){
        int row = wr*64 + m*16 + d;
        int slot = (oi&8) | ((oi&7) ^ (row&7));
        af[m] = *(const bf16x8*)(As + row*128 + slot*8);
      }
      #pragma unroll
      for (int n=0;n<4;n++){
        int col = wc*64 + n*16 + d;
        int slot = (oi&8) | ((oi&7) ^ (col&7));
        bfv[n] = *(const bf16x8*)(Bs + col*128 + slot*8);
      }
      #pragma unroll
      for (int m=0;m<4;m++)
        #pragma unroll
        for (int n=0;n<4;n++)
          acc[m][n] = __builtin_amdgcn_mfma_f32_16x16x32_bf16(af[m], bfv[n], acc[m][n], 0, 0, 0);
    }

    // remap: col<128 -> qx+col; col in [128,384) -> kv+(col-128); col>=384 -> qx+(col-256)
    short* dst; int coff;
    if (bn == 0)       { dst = qx; coff = 0;    }
    else if (bn < 384) { dst = kv; coff = -128; }
    else               { dst = qx; coff = -256; }

    #pragma unroll
    for (int m=0;m<4;m++){
      #pragma unroll
      for (int n=0;n<4;n++){
        int col = bn + wc*64 + n*16 + d;
        float bval = bias[col];
        #pragma unroll
        for (int j=0;j<4;j++){
          int row = bm + wr*64 + m*16 + lr*4 + j;
          if (row < Nrows){
            float v = acc[m][n][j] + bval;
            dst[(size_t)row*256 + col + coff] = f2b(v);
          }
        }
      }
    }
  }
}

// ---------------- fused FFN: relu(A@W1t^T+b1)@W2t^T + b2 + residual + LN2 ----------------
__global__ __launch_bounds__(256) void gemm_ffn_ln(
    const short* __restrict__ W1t,  // bf16 [512][128]
    const short* __restrict__ W2t,  // bf16 [128][512]
    const float* __restrict__ bias1,
    const float* __restrict__ bias2,
    short* __restrict__ hb,         // bf16 [N][128]: input A, residual, and output
    const float* __restrict__ g, const float* __restrict__ b,
    int Nrows)
{
  __shared__ short As[64*128];    // 16KB
  __shared__ short Bs[128*128];   // 32KB (current W1 chunk)
  __shared__ short F1[64*128];    // 16KB (ff1 tile, swizzled)
  __shared__ float red[2][64][2]; // 1KB
  int tid  = threadIdx.x;
  int lane = tid & 63;
  int wave = tid >> 6;
  int wr = wave >> 1, wc = wave & 1;
  int bm = blockIdx.x * 64;
  int d  = lane & 15;
  int lr = lane >> 4;

  #pragma unroll
  for (int it=0; it<4; ++it){
    int rbase = wave*16 + it*4;
    int r = rbase + lr;
    int oct = (d & 8) | ((d & 7) ^ (r & 7));
    int gr = bm + r; if (gr >= Nrows) gr = Nrows-1;
    gload16(hb + (size_t)gr*128 + oct*8, As + rbase*128);
  }

  f32x4 zero = {0.f,0.f,0.f,0.f};
  f32x4 acc2[2][4];
  #pragma unroll
  for (int m=0;m<2;m++)
    #pragma unroll
    for (int n=0;n<4;n++) acc2[m][n] = zero;

  for (int t=0; t<4; ++t){
    #pragma unroll
    for (int it=0; it<8; ++it){
      int rbase = wave*32 + it*4;
      int r = rbase + lr;
      int oct = (d & 8) | ((d & 7) ^ (r & 7));
      gload16(W1t + (size_t)(t*128 + r)*128 + oct*8, Bs + rbase*128);
    }
    __syncthreads();

    f32x4 acc1[2][4];
    #pragma unroll
    for (int m=0;m<2;m++)
      #pragma unroll
      for (int n=0;n<4;n++) acc1[m][n] = zero;
    #pragma unroll
    for (int ks=0; ks<4; ++ks){
      int oi = ks*4 + lr;
      bf16x8 af[2], bfv[4];
      #pragma unroll
      for (int m=0;m<2;m++){
        int row = wr*32 + m*16 + d;
        int slot = (oi&8) | ((oi&7) ^ (row&7));
        af[m] = *(const bf16x8*)(As + row*128 + slot*8);
      }
      #pragma unroll
      for (int n=0;n<4;n++){
        int cn = wc*64 + n*16 + d;
        int slot = (oi&8) | ((oi&7) ^ (cn&7));
        bfv[n] = *(const bf16x8*)(Bs + cn*128 + slot*8);
      }
      #pragma unroll
      for (int m=0;m<2;m++)
        #pragma unroll
        for (int n=0;n<4;n++)
          acc1[m][n] = __builtin_amdgcn_mfma_f32_16x16x32_bf16(af[m], bfv[n], acc1[m][n], 0, 0, 0);
    }
    __syncthreads();

    #pragma unroll
    for (int m=0;m<2;m++){
      #pragma unroll
      for (int n=0;n<4;n++){
        int col = wc*64 + n*16 + d;
        float bv1 = bias1[t*128 + col];
        int oct2 = col >> 3, within = col & 7;
        #pragma unroll
        for (int j=0;j<4;j++){
          int row = wr*32 + m*16 + lr*4 + j;
          float v = fmaxf(acc1[m][n][j] + bv1, 0.f);
          int so = (oct2 & 8) | ((oct2 & 7) ^ (row & 7));
          F1[row*128 + so*8 + within] = f2b(v);
        }
      }
    }
    __syncthreads();

    #pragma unroll
    for (int ks=0; ks<4; ++ks){
      int oi = ks*4 + lr;
      bf16x8 af[2], bfv[4];
      #pragma unroll
      for (int m=0;m<2;m++){
        int row = wr*32 + m*16 + d;
        int slot = (oi&8) | ((oi&7) ^ (row&7));
        af[m] = *(const bf16x8*)(F1 + row*128 + slot*8);
      }
      #pragma unroll
      for (int n=0;n<4;n++){
        int col = wc*64 + n*16 + d;
        bfv[n] = *(const bf16x8*)(W2t + (size_t)col*512 + t*128 + oi*8);
      }
      #pragma unroll
      for (int m=0;m<2;m++)
        #pragma unroll
        for (int n=0;n<4;n++)
          acc2[m][n] = __builtin_amdgcn_mfma_f32_16x16x32_bf16(af[m], bfv[n], acc2[m][n], 0, 0, 0);
    }
  }

  #pragma unroll
  for (int m=0;m<2;m++){
    #pragma unroll
    for (int n=0;n<4;n++){
      int col = wc*64 + n*16 + d;
      float bval = bias2[col];
      #pragma unroll
      for (int j=0;j<4;j++){
        int row = wr*32 + m*16 + lr*4 + j;
        int grow = bm + row; if (grow >= Nrows) grow = Nrows-1;
        acc2[m][n][j] += bval + b2f_s(hb[(size_t)grow*DIM + col]);
      }
    }
  }
  #pragma unroll
  for (int m=0;m<2;m++){
    #pragma unroll
    for (int j=0;j<4;j++){
      float ps = 0.f, pq = 0.f;
      #pragma unroll
      for (int n=0;n<4;n++){ float v = acc2[m][n][j]; ps += v; pq += v*v; }
      #pragma unroll
      for (int msk=1; msk<16; msk<<=1){ ps += __shfl_xor(ps, msk); pq += __shfl_xor(pq, msk); }
      if (d == 0){
        int row = wr*32 + m*16 + lr*4 + j;
        red[wc][row][0] = ps;
        red[wc][row][1] = pq;
      }
    }
  }
  __syncthreads();
  #pragma unroll
  for (int m=0;m<2;m++){
    #pragma unroll
    for (int j=0;j<4;j++){
      int row = wr*32 + m*16 + lr*4 + j;
      float S = red[0][row][0] + red[1][row][0];
      float Q = red[0][row][1] + red[1][row][1];
      float mu  = S*(1.f/128.f);
      float var = fmaxf(Q*(1.f/128.f) - mu*mu, 0.f);
      float rr  = rsqrtf(var + 1e-5f);
      int grow = bm + row;
      if (grow < Nrows){
        #pragma unroll
        for (int n=0;n<4;n++){
          int col = wc*64 + n*16 + d;
          float o = (acc2[m][n][j]-mu)*rr*g[col] + b[col];
          hb[(size_t)grow*DIM + col] = f2b(o);
        }
      }
    }
  }
}

// ---------------- fused edge attention + beta gate + LN1 ----------------
// 16 lanes per dst node, 8 ch/lane, degree-DESCENDING order, 2-edge unroll,
// src-index software pipeline, compact kv[N][256] gather array.
__global__ __launch_bounds__(256) void edge_attn_fused(
  const short* __restrict__ kv,       // bf16 [N][256]: k|v
  const short* __restrict__ qx,       // bf16 [N][256]: q|xr
  const short* __restrict__ ea_s, const int* __restrict__ src_s,
  const float* __restrict__ Wel, const float* __restrict__ bel,
  const int* __restrict__ row_start, const int* __restrict__ perm,
  short* __restrict__ hb,
  const float* __restrict__ Wb, const float* __restrict__ g, const float* __restrict__ b)
{
  int wid = (blockIdx.x*256 + threadIdx.x) >> 4;
  if (wid >= N_NODES) return;
  int node = perm[N_NODES - 1 - wid];   // highest degree first
  int ln = threadIdx.x & 15;
  int c0 = ln*8;

  const short* qrow = qx + (size_t)node*256;
  uint4 qu = *(const uint4*)(qrow + c0);
  float q0=b2f_lo(qu.x), q1=b2f_hi(qu.x), q2=b2f_lo(qu.y), q3=b2f_hi(qu.y);
  float q4=b2f_lo(qu.z), q5=b2f_hi(qu.z), q6=b2f_lo(qu.w), q7=b2f_hi(qu.w);

  float u[12];
  #pragma unroll
  for (int j=0;j<12;j++){
    float4 wA = *(const float4*)(Wel + j*DIM + c0);
    float4 wB = *(const float4*)(Wel + j*DIM + c0 + 4);
    float pp = q0*wA.x+q1*wA.y+q2*wA.z+q3*wA.w
             + q4*wB.x+q5*wB.y+q6*wB.z+q7*wB.w;
    u[j] = pp + __shfl_xor(pp,1);
  }
  float4 beA = *(const float4*)(bel + c0);
  float4 beB = *(const float4*)(bel + c0 + 4);
  float qbe;
  { float pp = q0*beA.x+q1*beA.y+q2*beA.z+q3*beA.w
             + q4*beB.x+q5*beB.y+q6*beB.z+q7*beB.w;
    qbe = pp + __shfl_xor(pp,1); }

  int rs = row_start[node], re = row_start[node+1];
  float den = 0.f;
  float av[8] = {0.f,0.f,0.f,0.f,0.f,0.f,0.f,0.f};
  float aEA[12] = {0.f,0.f,0.f,0.f,0.f,0.f,0.f,0.f,0.f,0.f,0.f,0.f};

  int npairs = (re - rs) >> 1;
  int s0 = 0, s1 = 0;
  if (npairs > 0){ s0 = src_s[rs]; s1 = src_s[rs+1]; }
  for (int p=0; p<npairs; ++p){
    int i = rs + p*2;
    int s0n = 0, s1n = 0;
    if (p+1 < npairs){ s0n = src_s[i+2]; s1n = src_s[i+3]; }
    const short* e0p = ea_s + (size_t)i*EDIM;
    uint2 a00 = *(const uint2*)(e0p);
    uint2 a01 = *(const uint2*)(e0p+4);
    uint2 a02 = *(const uint2*)(e0p+8);
    uint2 a10 = *(const uint2*)(e0p+12);
    uint2 a11 = *(const uint2*)(e0p+16);
    uint2 a12 = *(const uint2*)(e0p+20);
    const short* r0p = kv + (size_t)s0*256;
    const short* r1p = kv + (size_t)s1*256;
    uint4 ku0 = *(const uint4*)(r0p + c0);
    uint4 vu0 = *(const uint4*)(r0p + 128 + c0);
    uint4 ku1 = *(const uint4*)(r1p + c0);
    uint4 vu1 = *(const uint4*)(r1p + 128 + c0);

    float ea0[12], ea1[12];
    ea0[0]=b2f_lo(a00.x); ea0[1]=b2f_hi(a00.x); ea0[2]=b2f_lo(a00.y); ea0[3]=b2f_hi(a00.y);
    ea0[4]=b2f_lo(a01.x); ea0[5]=b2f_hi(a01.x); ea0[6]=b2f_lo(a01.y); ea0[7]=b2f_hi(a01.y);
    ea0[8]=b2f_lo(a02.x); ea0[9]=b2f_hi(a02.x); ea0[10]=b2f_lo(a02.y); ea0[11]=b2f_hi(a02.y);
    ea1[0]=b2f_lo(a10.x); ea1[1]=b2f_hi(a10.x); ea1[2]=b2f_lo(a10.y); ea1[3]=b2f_hi(a10.y);
    ea1[4]=b2f_lo(a11.x); ea1[5]=b2f_hi(a11.x); ea1[6]=b2f_lo(a11.y); ea1[7]=b2f_hi(a11.y);
    ea1[8]=b2f_lo(a12.x); ea1[9]=b2f_hi(a12.x); ea1[10]=b2f_lo(a12.y); ea1[11]=b2f_hi(a12.y);

    float pp0 = q0*b2f_lo(ku0.x) + q1*b2f_hi(ku0.x) + q2*b2f_lo(ku0.y) + q3*b2f_hi(ku0.y)
              + q4*b2f_lo(ku0.z) + q5*b2f_hi(ku0.z) + q6*b2f_lo(ku0.w) + q7*b2f_hi(ku0.w);
    float pp1 = q0*b2f_lo(ku1.x) + q1*b2f_hi(ku1.x) + q2*b2f_lo(ku1.y) + q3*b2f_hi(ku1.y)
              + q4*b2f_lo(ku1.z) + q5*b2f_hi(ku1.z) + q6*b2f_lo(ku1.w) + q7*b2f_hi(ku1.w);
    float al0 = pp0 + __shfl_xor(pp0,1) + qbe;
    float al1 = pp1 + __shfl_xor(pp1,1) + qbe;
    #pragma unroll
    for (int j=0;j<12;j++){ al0 += ea0[j]*u[j]; al1 += ea1[j]*u[j]; }
    float p0 = __expf(al0 * ASCALE);
    float p1 = __expf(al1 * ASCALE);
    den += p0 + p1;
    av[0] += p0*b2f_lo(vu0.x) + p1*b2f_lo(vu1.x);
    av[1] += p0*b2f_hi(vu0.x) + p1*b2f_hi(vu1.x);
    av[2] += p0*b2f_lo(vu0.y) + p1*b2f_lo(vu1.y);
    av[3] += p0*b2f_hi(vu0.y) + p1*b2f_hi(vu1.y);
    av[4] += p0*b2f_lo(vu0.z) + p1*b2f_lo(vu1.z);
    av[5] += p0*b2f_hi(vu0.z) + p1*b2f_hi(vu1.z);
    av[6] += p0*b2f_lo(vu0.w) + p1*b2f_lo(vu1.w);
    av[7] += p0*b2f_hi(vu0.w) + p1*b2f_hi(vu1.w);
    #pragma unroll
    for (int j=0;j<12;j++) aEA[j] += p0*ea0[j] + p1*ea1[j];
    s0 = s0n; s1 = s1n;
  }
  {
    int i = rs + npairs*2;
    if (i < re){
      int s = src_s[i];
      const short* eap = ea_s + (size_t)i*EDIM;
      uint2 eu0 = *(const uint2*)(eap);
      uint2 eu1 = *(const uint2*)(eap+4);
      uint2 eu2 = *(const uint2*)(eap+8);
      float ea0[12];
      ea0[0]=b2f_lo(eu0.x); ea0[1]=b2f_hi(eu0.x); ea0[2]=b2f_lo(eu0.y); ea0[3]=b2f_hi(eu0.y);
      ea0[4]=b2f_lo(eu1.x); ea0[5]=b2f_hi(eu1.x); ea0[6]=b2f_lo(eu1.y); ea0[7]=b2f_hi(eu1.y);
      ea0[8]=b2f_lo(eu2.x); ea0[9]=b2f_hi(eu2.x); ea0[10]=b2f_lo(eu2.y); ea0[11]=b2f_hi(eu2.y);
      const short* srow = kv + (size_t)s*256;
      uint4 ku = *(const uint4*)(srow + c0);
      uint4 vu = *(const uint4*)(srow + 128 + c0);
      float pp = q0*b2f_lo(ku.x) + q1*b2f_hi(ku.x) + q2*b2f_lo(ku.y) + q3*b2f_hi(ku.y)
               + q4*b2f_lo(ku.z) + q5*b2f_hi(ku.z) + q6*b2f_lo(ku.w) + q7*b2f_hi(ku.w);
      float alpha = pp + __shfl_xor(pp,1) + qbe;
      #pragma unroll
      for (int j=0;j<12;j++) alpha += ea0[j]*u[j];
      float p = __expf(alpha * ASCALE);
      den += p;
      av[0] += p*b2f_lo(vu.x); av[1] += p*b2f_hi(vu.x);
      av[2] += p*b2f_lo(vu.y); av[3] += p*b2f_hi(vu.y);
      av[4] += p*b2f_lo(vu.z); av[5] += p*b2f_hi(vu.z);
      av[6] += p*b2f_lo(vu.w); av[7] += p*b2f_hi(vu.w);
      #pragma unroll
      for (int j=0;j<12;j++) aEA[j] += p*ea0[j];
    }
  }

  float inv = 1.f/(den + 1e-16f);
  float gg[8];
  #pragma unroll
  for (int c=0;c<8;c++) gg[c] = av[c]*inv;
  #pragma unroll
  for (int j=0;j<12;j++){
    float wgt = aEA[j]*inv;
    float4 wA = *(const float4*)(Wel + j*DIM + c0);
    float4 wB = *(const float4*)(Wel + j*DIM + c0 + 4);
    gg[0]+=wgt*wA.x; gg[1]+=wgt*wA.y; gg[2]+=wgt*wA.z; gg[3]+=wgt*wA.w;
    gg[4]+=wgt*wB.x; gg[5]+=wgt*wB.y; gg[6]+=wgt*wB.z; gg[7]+=wgt*wB.w;
  }
  if (re > rs){
    gg[0]+=beA.x; gg[1]+=beA.y; gg[2]+=beA.z; gg[3]+=beA.w;
    gg[4]+=beB.x; gg[5]+=beB.y; gg[6]+=beB.z; gg[7]+=beB.w;
  }

  // beta gate (residual from bf16 hb)
  uint4 xu = *(const uint4*)(qrow + 128 + c0);
  float x[8];
  x[0]=b2f_lo(xu.x); x[1]=b2f_hi(xu.x); x[2]=b2f_lo(xu.y); x[3]=b2f_hi(xu.y);
  x[4]=b2f_lo(xu.z); x[5]=b2f_hi(xu.z); x[6]=b2f_lo(xu.w); x[7]=b2f_hi(xu.w);
  uint4 hu = *(const uint4*)(hb + (size_t)node*DIM + c0);
  float hv[8];
  unp8(hu, hv);
  float4 waA = *(const float4*)(Wb + c0),       waB = *(const float4*)(Wb + c0 + 4);
  float4 wxA = *(const float4*)(Wb + DIM + c0), wxB = *(const float4*)(Wb + DIM + c0 + 4);
  float4 wdA = *(const float4*)(Wb + 2*DIM + c0), wdB = *(const float4*)(Wb + 2*DIM + c0 + 4);
  float wa[8] = {waA.x,waA.y,waA.z,waA.w,waB.x,waB.y,waB.z,waB.w};
  float wx[8] = {wxA.x,wxA.y,wxA.z,wxA.w,wxB.x,wxB.y,wxB.z,wxB.w};
  float wd[8] = {wdA.x,wdA.y,wdA.z,wdA.w,wdB.x,wdB.y,wdB.z,wdB.w};
  float sacc = 0.f;
  #pragma unroll
  for (int c=0;c<8;c++) sacc += gg[c]*wa[c] + x[c]*wx[c] + (gg[c]-x[c])*wd[c];
  sacc = sum16(sacc);
  float beta = 1.f/(1.f + __expf(-sacc));
  float t[8], ts = 0.f;
  #pragma unroll
  for (int c=0;c<8;c++){ t[c] = beta*x[c] + (1.f-beta)*gg[c] + hv[c]; ts += t[c]; }
  float mu = sum16(ts)*(1.f/128.f);
  float vs = 0.f;
  #pragma unroll
  for (int c=0;c<8;c++){ t[c] -= mu; vs += t[c]*t[c]; }
  float var = sum16(vs)*(1.f/128.f);
  float r = rsqrtf(var + 1e-5f);
  float4 gA = *(const float4*)(g + c0), gB = *(const float4*)(g + c0 + 4);
  float4 bA = *(const float4*)(b + c0), bB = *(const float4*)(b + c0 + 4);
  float gv[8] = {gA.x,gA.y,gA.z,gA.w,gB.x,gB.y,gB.z,gB.w};
  float bv[8] = {bA.x,bA.y,bA.z,bA.w,bB.x,bB.y,bB.z,bB.w};
  float o[8];
  #pragma unroll
  for (int c=0;c<8;c++) o[c] = t[c]*r*gv[c] + bv[c];
  uint4 ou;
  ou.x = (unsigned int)(unsigned short)f2b(o[0]) | ((unsigned int)(unsigned short)f2b(o[1])<<16);
  ou.y = (unsigned int)(unsigned short)f2b(o[2]) | ((unsigned int)(unsigned short)f2b(o[3])<<16);
  ou.z = (unsigned int)(unsigned short)f2b(o[4]) | ((unsigned int)(unsigned short)f2b(o[5])<<16);
  ou.w = (unsigned int)(unsigned short)f2b(o[6]) | ((unsigned int)(unsigned short)f2b(o[7])<<16);
  *(uint4*)(hb + (size_t)node*DIM + c0) = ou;
}

// ---------------- segmented mean pool + output projection (256 threads) ----------------
__global__ __launch_bounds__(256) void pool_out(
  const short* __restrict__ hb, const int* __restrict__ batch,
  const float* __restrict__ Wout, const float* __restrict__ bout,
  float* __restrict__ out)
{
  int bidx = blockIdx.x;
  int d = threadIdx.x & 127;
  int half = threadIdx.x >> 7;
  __shared__ int seg[2];
  __shared__ float psum[2][DIM];
  __shared__ float p[DIM];
  if (threadIdx.x < 2){
    int target = bidx + threadIdx.x;
    int lo = 0, hi = N_NODES;
    while (lo < hi){ int mid = (lo+hi)>>1; if (batch[mid] < target) lo = mid+1; else hi = mid; }
    seg[threadIdx.x] = lo;
  }
  __syncthreads();
  int lo = seg[0], hi = seg[1];
  float s = 0.f;
  for (int n=lo+half; n<hi; n+=2) s += b2f_s(hb[(size_t)n*DIM + d]);
  psum[half][d] = s;
  __syncthreads();
  if (half == 0){
    float cnt = (float)(hi - lo);
    p[d] = (psum[0][d] + psum[1][d]) / fmaxf(cnt, 1.f);
  }
  __syncthreads();
  float o = 0.f;
  #pragma unroll 8
  for (int kk=half*64; kk<half*64+64; ++kk) o += p[kk]*Wout[kk*DIM + d];
  psum[half][d] = o;
  __syncthreads();
  if (half == 0) out[bidx*DIM + d] = psum[0][d] + psum[1][d] + bout[d];
}

extern "C" void kernel_launch(void* const* d_in, const int* in_sizes, int n_in,
                              void* d_out, int out_size, void* d_ws, size_t ws_size,
                              hipStream_t stream)
{
  const float* x     = (const float*)d_in[0];
  const float* ea    = (const float*)d_in[1];
  const int*   ei    = (const int*)d_in[2];
  const int*   batch = (const int*)d_in[3];
  const float* Wemb  = (const float*)d_in[4];
  const float* bemb  = (const float*)d_in[5];
  const float* Wout  = (const float*)d_in[6];
  const float* bout  = (const float*)d_in[7];
  const float* Wq    = (const float*)d_in[8];
  const float* bq    = (const float*)d_in[9];
  const float* Wk    = (const float*)d_in[10];
  const float* bk    = (const float*)d_in[11];
  const float* Wv    = (const float*)d_in[12];
  const float* bv    = (const float*)d_in[13];
  const float* We    = (const float*)d_in[14];
  const float* be    = (const float*)d_in[15];
  const float* Wskip = (const float*)d_in[16];
  const float* bskip = (const float*)d_in[17];
  const float* Wbeta = (const float*)d_in[18];
  const float* g1    = (const float*)d_in[19];
  const float* b1    = (const float*)d_in[20];
  const float* g2    = (const float*)d_in[21];
  const float* b2    = (const float*)d_in[22];
  const float* Wf1   = (const float*)d_in[23];
  const float* bf1   = (const float*)d_in[24];
  const float* Wf2   = (const float*)d_in[25];
  const float* bf2   = (const float*)d_in[26];
  float* out = (float*)d_out;

  // ---- workspace layout ----
  float* ws     = (float*)d_ws;
  float* bqkvs  = ws;                                  // L*512
  short* ea_s   = (short*)(bqkvs + LAYERS*512);        // E*12 (bf16)
  short* hb     = ea_s + (size_t)N_EDGES*EDIM;         // N*128
  short* kv     = hb + (size_t)N_NODES*DIM;            // N*256 (k|v, gather hot set)
  short* qx     = kv + (size_t)N_NODES*256;            // N*256 (q|xr)
  short* xb     = qx + (size_t)N_NODES*256;            // N*128
  short* wemb_t = xb + (size_t)N_NODES*DIM;            // 128*128
  short* wq_t   = wemb_t + DIM*DIM;                    // L*512*128
  short* wf1_t  = wq_t  + (size_t)LAYERS*NDFF*DIM;
  short* wf2_t  = wf1_t + (size_t)LAYERS*NDFF*DIM;
  int*   cnt       = (int*)(wf2_t + (size_t)LAYERS*NDFF*DIM);
  int*   cnt2      = cnt + N_NODES;
  int*   row_start = cnt2 + N_NODES;                   // N+1
  int*   bsum      = row_start + N_NODES + 1;          // 64
  int*   dhist     = bsum + 64;                        // 256
  int*   dcnt      = dhist + 256;                      // 256
  int*   dstart    = dcnt + 256;                       // 256
  int*   node_perm = dstart + 256;                     // N
  int*   src_s     = node_perm + N_NODES;              // E

  hipMemsetAsync(cnt,  0, N_NODES*sizeof(int), stream);
  hipMemsetAsync(cnt2, 0, N_NODES*sizeof(int), stream);
  hipMemsetAsync(dhist, 0, 512*sizeof(int), stream);   // dhist + dcnt

  const int NB_SCAN = (N_NODES + 1023)/1024;           // 49
  const int NB_DEG  = (N_NODES + 255)/256;             // 196
  count_kernel<<<(N_EDGES+255)/256, 256, 0, stream>>>(ei, cnt);
  scan1<<<NB_SCAN, 1024, 0, stream>>>(cnt, row_start, bsum);
  scan2<<<1, 64, 0, stream>>>(bsum, NB_SCAN);
  scan3<<<(N_NODES+255)/256, 256, 0, stream>>>(row_start, bsum);
  deg_hist<<<NB_DEG, 256, 0, stream>>>(cnt, dhist);
  deg_scan<<<1, 256, 0, stream>>>(dhist, dstart);
  deg_place<<<NB_DEG, 256, 0, stream>>>(cnt, dcnt, dstart, node_perm);
  scatter_kernel<<<(N_EDGES+255)/256, 256, 0, stream>>>(ei, ea, cnt2, row_start, src_s, ea_s);

  pack_weights<<<dim3(768, LAYERS), 256, 0, stream>>>(
      Wq, Wk, Wv, Wskip, bq, bk, bv, bskip, Wf1, Wf2, wq_t, wf1_t, wf2_t, bqkvs);
  pack_emb<<<64, 256, 0, stream>>>(Wemb, wemb_t);
  cast_pad_x<<<(N_NODES*64 + 255)/256, 256, 0, stream>>>(x, xb);

  int gM  = (N_NODES + 127)/128;                       // 391
  int gM64 = (N_NODES + 63)/64;                        // 782
  int attnBlocks = (N_NODES*16 + 255)/256;             // 3125

  // hb = bf16(x @ Wemb + bemb) via MFMA
  gemm_k128<<<dim3(gM, 1), 256, 0, stream>>>(xb, wemb_t, bemb, hb, N_NODES, DIM, 0, 1);

  for (int l=0; l<LAYERS; ++l){
    // fused Q|K|V|skip projection -> kv[N][256] + qx[N][256]
    gemm_qkvs<<<dim3(gM, 2), 256, 0, stream>>>(
        hb, wq_t + (size_t)l*NDFF*DIM, bqkvs + l*512, kv, qx, N_NODES, 2);

    // attention + beta gate + LN1 -> hb
    edge_attn_fused<<<attnBlocks, 256, 0, stream>>>(
        kv, qx, ea_s, src_s, We + (size_t)l*EDIM*DIM, be + l*DIM, row_start, node_perm,
        hb, Wbeta + l*3*DIM, g1 + l*DIM, b1 + l*DIM);

    // fused FF1+FF2 + residual + LN2 -> hb  (ff1 never touches HBM)
    gemm_ffn_ln<<<dim3(gM64, 1), 256, 0, stream>>>(
        wf1_t + (size_t)l*NDFF*DIM, wf2_t + (size_t)l*DIM*NDFF,
        bf1 + l*NDFF, bf2 + l*DIM, hb,
        g2 + l*DIM, b2 + l*DIM, N_NODES);
  }

  pool_out<<<NBATCH, 256, 0, stream>>>(hb, batch, Wout, bout, out);
}